// Round 8
// baseline (256.799 us; speedup 1.0000x reference)
//
#include <hip/hip_runtime.h>

#define K 8

typedef float    f32x2 __attribute__((ext_vector_type(2)));
typedef int      i32x2 __attribute__((ext_vector_type(2)));
typedef unsigned u32x4 __attribute__((ext_vector_type(4)));

static __device__ __forceinline__ unsigned quant10(float v) {
    v = fminf(fmaxf(v, -1.0f), 1.0f);
    return (unsigned)__float2uint_rn((v + 1.0f) * 511.5f);   // [0,1023]
}

// ---- pass 1: faces + vn -> per-face quantized normal table (16 B/face) ----
__global__ __launch_bounds__(256) void pack_face_normals_q10(
    const int*   __restrict__ faces,
    const float* __restrict__ vn,
    u32x4*       __restrict__ tbl,
    int F)
{
    int f = blockIdx.x * blockDim.x + threadIdx.x;
    if (f >= F) return;
    int v0 = faces[3 * f + 0];
    int v1 = faces[3 * f + 1];
    int v2 = faces[3 * f + 2];
    u32x4 r;
    r.x = quant10(vn[3 * v0 + 0]) | (quant10(vn[3 * v0 + 1]) << 10) | (quant10(vn[3 * v0 + 2]) << 20);
    r.y = quant10(vn[3 * v1 + 0]) | (quant10(vn[3 * v1 + 1]) << 10) | (quant10(vn[3 * v1 + 2]) << 20);
    r.z = quant10(vn[3 * v2 + 0]) | (quant10(vn[3 * v2 + 1]) << 10) | (quant10(vn[3 * v2 + 2]) << 20);
    r.w = 0u;
    tbl[f] = r;
}

// decode+shade one fragment: given rec (3x10-bit packed), bary b0..b2 (pre-masked)
// returns c = S * (b·v) - (b0+b1+b2)  per component   [since dq = v*S - 1]
static __device__ __forceinline__ void shade_frag(
    u32x4 rec, float b0, float b1, float b2,
    float& c0, float& c1, float& c2)
{
    const float S = 2.0f / 1023.0f;
    float t = b0 + b1 + b2;
    float v00 = (float)( rec.x        & 1023u), v01 = (float)((rec.x >> 10) & 1023u), v02 = (float)((rec.x >> 20) & 1023u);
    float v10 = (float)( rec.y        & 1023u), v11 = (float)((rec.y >> 10) & 1023u), v12 = (float)((rec.y >> 20) & 1023u);
    float v20 = (float)( rec.z        & 1023u), v21 = (float)((rec.z >> 10) & 1023u), v22 = (float)((rec.z >> 20) & 1023u);
    c0 = fmaf(S, fmaf(v00, b0, fmaf(v10, b1, v20 * b2)), -t);
    c1 = fmaf(S, fmaf(v01, b0, fmaf(v11, b1, v21 * b2)), -t);
    c2 = fmaf(S, fmaf(v02, b0, fmaf(v12, b1, v22 * b2)), -t);
}

// ---- pass 2: 4 threads/pixel, 2 adjacent fragments each ----
__global__ __launch_bounds__(256) void shade_blend_frag2(
    const float* __restrict__ bary,   // [P,K,3]
    const float* __restrict__ zbuf,   // [P,K]
    const float* __restrict__ dists,  // [P,K]
    const int*   __restrict__ p2f,    // [P,K]
    const u32x4* __restrict__ tbl,    // [F]
    float*       __restrict__ out,    // [P,4]
    int T4)                           // P*4
{
    const float SIGMA_INV = 1e4f;
    const float GAMMA_INV = 1e4f;
    const float EPSV      = 1e-10f;
    const float ZFAR      = 100.0f;
    const float ZSCALE    = 1.0f / 99.0f;

    int tid = blockIdx.x * blockDim.x + threadIdx.x;
    if (tid >= T4) return;
    int pix = tid >> 2;
    int q   = tid & 3;
    size_t base = (size_t)pix * K + 2 * q;    // first fragment index (even)

    // coalesced paired streaming loads (8 B/lane)
    i32x2 f2 = __builtin_nontemporal_load(reinterpret_cast<const i32x2*>(p2f   + base));
    f32x2 z2 = __builtin_nontemporal_load(reinterpret_cast<const f32x2*>(zbuf  + base));
    f32x2 d2 = __builtin_nontemporal_load(reinterpret_cast<const f32x2*>(dists + base));
    const float* bb = bary + base * 3;        // 6 floats, 8-B aligned
    f32x2 bv0 = __builtin_nontemporal_load(reinterpret_cast<const f32x2*>(bb + 0));
    f32x2 bv1 = __builtin_nontemporal_load(reinterpret_cast<const f32x2*>(bb + 2));
    f32x2 bv2 = __builtin_nontemporal_load(reinterpret_cast<const f32x2*>(bb + 4));

    // two independent 16 B gathers in flight
    int fi0 = f2.x >= 0 ? f2.x : 0;
    int fi1 = f2.y >= 0 ? f2.y : 0;
    u32x4 rec0 = tbl[fi0];
    u32x4 rec1 = tbl[fi1];

    float mf0 = f2.x >= 0 ? 1.0f : 0.0f;
    float mf1 = f2.y >= 0 ? 1.0f : 0.0f;

    float p0 = mf0 / (1.0f + __expf(d2.x * SIGMA_INV));
    float p1 = mf1 / (1.0f + __expf(d2.y * SIGMA_INV));
    float zi0 = (ZFAR - z2.x) * ZSCALE * mf0;
    float zi1 = (ZFAR - z2.y) * ZSCALE * mf1;

    float c00, c01, c02, c10, c11, c12;
    shade_frag(rec0, bv0.x * mf0, bv0.y * mf0, bv1.x * mf0, c00, c01, c02);
    shade_frag(rec1, bv1.y * mf1, bv2.x * mf1, bv2.y * mf1, c10, c11, c12);

    // pixel max over 4 lanes (local pair first)
    float zmax = fmaxf(fmaxf(zi0, zi1), EPSV);
    zmax = fmaxf(zmax, __shfl_xor(zmax, 1));
    zmax = fmaxf(zmax, __shfl_xor(zmax, 2));

    float w0 = p0 * __expf((zi0 - zmax) * GAMMA_INV);
    float w1 = p1 * __expf((zi1 - zmax) * GAMMA_INV);
    float w  = w0 + w1;
    float a0 = w0 * c00 + w1 * c10;
    float a1 = w0 * c01 + w1 * c11;
    float a2 = w0 * c02 + w1 * c12;
    float pm = (1.0f - p0) * (1.0f - p1);

#pragma unroll
    for (int m = 1; m <= 2; m <<= 1) {
        w  += __shfl_xor(w,  m);
        a0 += __shfl_xor(a0, m);
        a1 += __shfl_xor(a1, m);
        a2 += __shfl_xor(a2, m);
        pm *= __shfl_xor(pm, m);
    }

    float delta = __expf((EPSV - zmax) * GAMMA_INV);
    float invd  = 1.0f / (w + delta);
    float bgw   = delta * invd;        // background = (1,1,1)

    float val = (q == 0) ? a0 * invd + bgw
              : (q == 1) ? a1 * invd + bgw
              : (q == 2) ? a2 * invd + bgw
              :            1.0f - pm;
    __builtin_nontemporal_store(val, out + (size_t)pix * 4 + q);
}

// ---- fallback (workspace too small): two-level gather, 1 px/thread ----
__global__ __launch_bounds__(256) void shade_blend_direct(
    const float* __restrict__ bary, const float* __restrict__ zbuf,
    const float* __restrict__ dists, const float* __restrict__ vn,
    const int* __restrict__ p2f, const int* __restrict__ faces,
    float* __restrict__ out, int P)
{
    const float SIGMA_INV = 1e4f, GAMMA_INV = 1e4f, EPSV = 1e-10f;
    const float ZFAR = 100.0f, ZSCALE = 1.0f / 99.0f;
    int pix = blockIdx.x * blockDim.x + threadIdx.x;
    if (pix >= P) return;
    const float4* zb4 = reinterpret_cast<const float4*>(zbuf  + (size_t)pix * K);
    const float4* ds4 = reinterpret_cast<const float4*>(dists + (size_t)pix * K);
    const int4*   pf4 = reinterpret_cast<const int4*>(p2f     + (size_t)pix * K);
    const float4* bc4 = reinterpret_cast<const float4*>(bary  + (size_t)pix * K * 3);
    float4 za = zb4[0], zb_ = zb4[1];
    float4 da = ds4[0], db_ = ds4[1];
    int4   fa = pf4[0], fb_ = pf4[1];
    float zk[K] = { za.x, za.y, za.z, za.w, zb_.x, zb_.y, zb_.z, zb_.w };
    float dk[K] = { da.x, da.y, da.z, da.w, db_.x, db_.y, db_.z, db_.w };
    int   fk[K] = { fa.x, fa.y, fa.z, fa.w, fb_.x, fb_.y, fb_.z, fb_.w };
    float barr[K * 3];
#pragma unroll
    for (int i = 0; i < 6; ++i) {
        float4 t = bc4[i];
        barr[4 * i + 0] = t.x; barr[4 * i + 1] = t.y;
        barr[4 * i + 2] = t.z; barr[4 * i + 3] = t.w;
    }
    float prob[K], zinv[K], c0[K], c1[K], c2[K];
    float zmax = EPSV;
#pragma unroll
    for (int kk = 0; kk < K; ++kk) {
        int fraw = fk[kk];
        float mf = fraw >= 0 ? 1.0f : 0.0f;
        int fi = fraw >= 0 ? fraw : 0;
        int v0 = faces[3 * fi + 0], v1 = faces[3 * fi + 1], v2 = faces[3 * fi + 2];
        float p = 1.0f / (1.0f + __expf(dk[kk] * SIGMA_INV));
        prob[kk] = p * mf;
        zinv[kk] = (ZFAR - zk[kk]) * ZSCALE * mf;
        zmax = fmaxf(zmax, zinv[kk]);
        float b0 = barr[3 * kk + 0] * mf, b1 = barr[3 * kk + 1] * mf, b2 = barr[3 * kk + 2] * mf;
        c0[kk] = b0 * vn[3 * v0 + 0] + b1 * vn[3 * v1 + 0] + b2 * vn[3 * v2 + 0];
        c1[kk] = b0 * vn[3 * v0 + 1] + b1 * vn[3 * v1 + 1] + b2 * vn[3 * v2 + 1];
        c2[kk] = b0 * vn[3 * v0 + 2] + b1 * vn[3 * v1 + 2] + b2 * vn[3 * v2 + 2];
    }
    float one_minus_prod = 1.0f, wsum = 0.0f, a0 = 0.0f, a1 = 0.0f, a2 = 0.0f;
#pragma unroll
    for (int kk = 0; kk < K; ++kk) {
        one_minus_prod *= (1.0f - prob[kk]);
        float w = prob[kk] * __expf((zinv[kk] - zmax) * GAMMA_INV);
        wsum += w; a0 += w * c0[kk]; a1 += w * c1[kk]; a2 += w * c2[kk];
    }
    float delta = __expf((EPSV - zmax) * GAMMA_INV);
    float inv_denom = 1.0f / (wsum + delta);
    float bgw = delta * inv_denom;
    float4 o;
    o.x = a0 * inv_denom + bgw; o.y = a1 * inv_denom + bgw;
    o.z = a2 * inv_denom + bgw; o.w = 1.0f - one_minus_prod;
    *reinterpret_cast<float4*>(out + (size_t)pix * 4) = o;
}

extern "C" void kernel_launch(void* const* d_in, const int* in_sizes, int n_in,
                              void* d_out, int out_size, void* d_ws, size_t ws_size,
                              hipStream_t stream) {
    const float* bary  = (const float*)d_in[0];
    const float* zbuf  = (const float*)d_in[1];
    const float* dists = (const float*)d_in[2];
    const float* vn    = (const float*)d_in[3];
    const int*   p2f   = (const int*)d_in[4];
    const int*   faces = (const int*)d_in[5];
    float* out = (float*)d_out;

    int P = out_size / 4;           // N*H*W pixels
    int F = in_sizes[5] / 3;        // faces
    int block = 256;

    size_t tbl_bytes = (size_t)F * 16;
    if (ws_size >= tbl_bytes) {
        u32x4* tbl = (u32x4*)d_ws;
        int gf = (F + block - 1) / block;
        pack_face_normals_q10<<<gf, block, 0, stream>>>(faces, vn, tbl, F);
        int T4 = P * 4;
        int grid = (T4 + block - 1) / block;
        shade_blend_frag2<<<grid, block, 0, stream>>>(bary, zbuf, dists, p2f, tbl, out, T4);
    } else {
        int grid = (P + block - 1) / block;
        shade_blend_direct<<<grid, block, 0, stream>>>(bary, zbuf, dists, vn, p2f, faces, out, P);
    }
}